// Round 7
// baseline (890.750 us; speedup 1.0000x reference)
//
#include <hip/hip_runtime.h>
#include <hip/hip_fp16.h>
#include <math.h>

#define NROWS 8192

typedef _Float16 half8 __attribute__((ext_vector_type(8)));
typedef _Float16 half4 __attribute__((ext_vector_type(4)));
typedef float f32x4 __attribute__((ext_vector_type(4)));
typedef float f32x16 __attribute__((ext_vector_type(16)));

__device__ __forceinline__ f32x4 mfma16(half8 a, half8 b, f32x4 c) {
  return __builtin_amdgcn_mfma_f32_16x16x32_f16(a, b, c, 0, 0, 0);
}
__device__ __forceinline__ f32x16 mfma32(half8 a, half8 b, f32x16 c) {
  return __builtin_amdgcn_mfma_f32_32x32x16_f16(a, b, c, 0, 0, 0);
}

// ---------------------------------------------------------------------------
// prep: x (f32)->xh (f16); 5 weights -> transposed f16 WT[wi][n][k] via LDS
// 64x64 transpose tiles. blocks 0..255: x. blocks 256..575: W tiles.
// ---------------------------------------------------------------------------
__global__ __launch_bounds__(256) void prep(
    const float* __restrict__ x,
    const float* __restrict__ Wq, const float* __restrict__ Wk,
    const float* __restrict__ Wv, const float* __restrict__ Wf,
    const float* __restrict__ Wp,
    _Float16* __restrict__ xh, _Float16* __restrict__ WT)
{
  __shared__ float Ws[64][68];
  const int bid = blockIdx.x, tid = threadIdx.x;
  if (bid < 256) {
    const int base = bid * 16384 + tid * 4;
#pragma unroll
    for (int r = 0; r < 16; ++r) {
      float4 v = *(const float4*)(x + base + r * 1024);
      half4 h;
      h[0] = (_Float16)v.x; h[1] = (_Float16)v.y;
      h[2] = (_Float16)v.z; h[3] = (_Float16)v.w;
      *(half4*)(xh + base + r * 1024) = h;
    }
  } else {
    const int wb = bid - 256;          // 0..319
    const int wi = wb >> 6;            // 0..4
    const int tix = wb & 63;
    const int k0 = (tix >> 3) * 64;
    const int n0 = (tix & 7) * 64;
    const float* W = (wi == 0) ? Wq : (wi == 1) ? Wk : (wi == 2) ? Wv
                   : (wi == 3) ? Wf : Wp;
    const int r = tid >> 2, cq = tid & 3;
#pragma unroll
    for (int j = 0; j < 4; ++j) {
      float4 v = *(const float4*)(W + (size_t)(k0 + r) * 512 + n0 + cq * 16 + j * 4);
      *(float4*)&Ws[r][cq * 16 + j * 4] = v;
    }
    __syncthreads();
    const int n = tid >> 2, kq = tid & 3;
    half8 h0, h1;
#pragma unroll
    for (int m = 0; m < 8; ++m) h0[m] = (_Float16)Ws[kq * 16 + m][n];
#pragma unroll
    for (int m = 0; m < 8; ++m) h1[m] = (_Float16)Ws[kq * 16 + 8 + m][n];
    _Float16* dst = WT + (size_t)wi * 262144 + (size_t)(n0 + n) * 512 + k0 + kq * 16;
    *(half8*)dst = h0;
    *(half8*)(dst + 8) = h1;
  }
}

// ---------------------------------------------------------------------------
// Fused QKV (round-2 proven shell): M-tile 32, grid 256, 8 waves, n-slice 64.
// A staged in LDS; B-frags from L2-resident WT. V written transposed.
// ---------------------------------------------------------------------------
__global__ __launch_bounds__(512, 2) void qkv(
    const _Float16* __restrict__ xh, const _Float16* __restrict__ WT,
    const float* __restrict__ bq, const float* __restrict__ bk,
    const float* __restrict__ bv,
    _Float16* __restrict__ Qh, _Float16* __restrict__ Kh,
    _Float16* __restrict__ Vt)
{
  __shared__ _Float16 As[32][520];
  const int M0 = blockIdx.x * 32;
  const int tid = threadIdx.x;
  const int lane = tid & 63;
  const int w = tid >> 6;
  const int lr = lane & 15;
  const int lkb = lane >> 4;

#pragma unroll
  for (int j = 0; j < 4; ++j) {
    int c = tid + 512 * j;
    int r = c >> 6, c16 = c & 63;
    half8 h = *(const half8*)(xh + (size_t)(M0 + r) * 512 + c16 * 8);
    *(half8*)&As[r][c16 * 8] = h;
  }
  __syncthreads();

  const _Float16* WqT = WT;
  const _Float16* WkT = WT + 262144;
  const _Float16* WvT = WT + 524288;

  f32x4 aq[2][4] = {}, ak[2][4] = {}, av[2][4] = {};

  for (int ks = 0; ks < 16; ++ks) {
    half8 a0 = *(const half8*)&As[lr][ks * 32 + lkb * 8];
    half8 a1 = *(const half8*)&As[16 + lr][ks * 32 + lkb * 8];
#pragma unroll
    for (int nt = 0; nt < 4; ++nt) {
      const size_t boff = (size_t)(w * 64 + nt * 16 + lr) * 512 + ks * 32 + lkb * 8;
      half8 bqf = *(const half8*)(WqT + boff);
      half8 bkf = *(const half8*)(WkT + boff);
      half8 bvf = *(const half8*)(WvT + boff);
      aq[0][nt] = mfma16(a0, bqf, aq[0][nt]);
      aq[1][nt] = mfma16(a1, bqf, aq[1][nt]);
      ak[0][nt] = mfma16(a0, bkf, ak[0][nt]);
      ak[1][nt] = mfma16(a1, bkf, ak[1][nt]);
      av[0][nt] = mfma16(a0, bvf, av[0][nt]);
      av[1][nt] = mfma16(a1, bvf, av[1][nt]);
    }
  }

#pragma unroll
  for (int mt = 0; mt < 2; ++mt) {
#pragma unroll
    for (int nt = 0; nt < 4; ++nt) {
      const int col = w * 64 + nt * 16 + lr;
      const float vbq = bq[col], vbk = bk[col], vbv = bv[col];
      const int row0 = M0 + mt * 16 + lkb * 4;
#pragma unroll
      for (int i = 0; i < 4; ++i) {
        Qh[(size_t)(row0 + i) * 512 + col] = (_Float16)(aq[mt][nt][i] + vbq);
        Kh[(size_t)(row0 + i) * 512 + col] = (_Float16)(ak[mt][nt][i] + vbk);
      }
      half4 pk;
#pragma unroll
      for (int i = 0; i < 4; ++i) pk[i] = (_Float16)(av[mt][nt][i] + vbv);
      *(half4*)(Vt + (size_t)col * NROWS + row0) = pk;
    }
  }
}

// ---------------------------------------------------------------------------
// Retention v5: 32x32x16 MFMA, register-heavy, L2-streaming.
// Block: 512 thr, I-tile 64, J-tile 128, nc=4 J-chunks (Jc = bid&3 -> XCD
// locality). 8 waves: QK role (ig = w>>2 i-group of 32, js = w&3 j-slice of
// 32); PV role (n-slice 64 = w*64). Q: 32 rows x K=512 in 128 VGPRs. K,V
// stream from L2 (no LDS). P (64x128 f16, XOR-swizzled 16KB) via LDS.
// D loaded coalesced + nontemporal (keeps L2 for K/V).
// ---------------------------------------------------------------------------
__global__ __launch_bounds__(512) __attribute__((amdgpu_waves_per_eu(2)))
void retention(
    const _Float16* __restrict__ Qh, const _Float16* __restrict__ Kh,
    const _Float16* __restrict__ Vt, const float* __restrict__ Dm,
    float* __restrict__ XpBase)
{
  __shared__ _Float16 Ps[64 * 128];   // 16 KB, chunk-XOR swizzled

  const int bid = blockIdx.x;
  const int Jc = bid & 3;
  const int I0 = (bid >> 2) * 64;
  const int Jbase = Jc * 2048;
  float* __restrict__ Xp = XpBase + (size_t)Jc * (NROWS * 512);

  const int tid = threadIdx.x;
  const int lane = tid & 63;
  const int l31 = lane & 31;
  const int hi = lane >> 5;
  const int w = tid >> 6;
  const int ig = w >> 2;      // 0..1
  const int js = w & 3;       // 0..3

  // Q A-frags: rows I0+ig*32+l31, k = s*16 + hi*8 .. +8  (128 VGPR)
  half8 q[32];
  {
    const _Float16* qp = Qh + (size_t)(I0 + ig * 32 + l31) * 512 + hi * 8;
#pragma unroll
    for (int s = 0; s < 32; ++s) q[s] = *(const half8*)(qp + s * 16);
  }

  f32x16 xacc[2][2] = {};

  for (int t = 0; t < 16; ++t) {
    const int J0 = Jbase + t * 128;
    const int jb = J0 + js * 32;

    // ---- D loads first (coalesced, nontemporal; latency hides under QK)
    float dv[16];
    {
      const float* dp = Dm + (size_t)(I0 + ig * 32) * NROWS + jb + l31;
#pragma unroll
      for (int r = 0; r < 16; ++r) {
        const int i = (r & 3) + 8 * (r >> 2) + 4 * hi;
        dv[r] = __builtin_nontemporal_load(dp + (size_t)i * NROWS);
      }
    }

    // ---- QK^T: S(32i x 32j) = q x K^T, K-frags streamed from L2
    f32x16 s = {};
    {
      const _Float16* kp = Kh + (size_t)(jb + l31) * 512 + hi * 8;
#pragma unroll
      for (int st = 0; st < 32; ++st)
        s = mfma32(q[st], *(const half8*)(kp + st * 16), s);
    }

    // ---- P = D*S -> f16 -> Ps (XOR-swizzled), scalar b16 writes
    {
      const int jj = js * 32 + l31;
      const int cbase = jj >> 3, jlow = jj & 7;
#pragma unroll
      for (int r = 0; r < 16; ++r) {
        const int i = ig * 32 + (r & 3) + 8 * (r >> 2) + 4 * hi;
        Ps[i * 128 + ((cbase ^ (i & 7)) * 8) + jlow] = (_Float16)(s[r] * dv[r]);
      }
    }
    __syncthreads();   // A: P complete

    // ---- PV: X(64i x 64n-slice) += P x V, V-frags streamed from L2
#pragma unroll
    for (int st = 0; st < 8; ++st) {
      const int cb = st * 2 + hi;
      half8 pa0 = *(const half8*)&Ps[l31 * 128 + ((cb ^ (l31 & 7)) * 8)];
      half8 pa1 = *(const half8*)&Ps[(32 + l31) * 128 + ((cb ^ (l31 & 7)) * 8)];
      const _Float16* vp = Vt + (size_t)(w * 64 + l31) * NROWS + J0 + st * 16 + hi * 8;
      half8 vb0 = *(const half8*)(vp);
      half8 vb1 = *(const half8*)(vp + (size_t)32 * NROWS);
      xacc[0][0] = mfma32(pa0, vb0, xacc[0][0]);
      xacc[0][1] = mfma32(pa0, vb1, xacc[0][1]);
      xacc[1][0] = mfma32(pa1, vb0, xacc[1][0]);
      xacc[1][1] = mfma32(pa1, vb1, xacc[1][1]);
    }
    __syncthreads();   // B: Ps free for next tile
  }

  // epilogue: C layout col=l31 (n), row=(r&3)+8*(r>>2)+4*hi (i)
#pragma unroll
  for (int i2 = 0; i2 < 2; ++i2)
#pragma unroll
    for (int nt = 0; nt < 2; ++nt)
#pragma unroll
      for (int r = 0; r < 16; ++r) {
        const int i = I0 + i2 * 32 + (r & 3) + 8 * (r >> 2) + 4 * hi;
        Xp[(size_t)i * 512 + w * 64 + nt * 32 + l31] = xacc[i2][nt][r];
      }
}

// ---------------------------------------------------------------------------
// Fused MLP (round-3 proven shell, M=32, grid 256): h = gelu((sum Xp)@Wf+bf);
// out = GroupNorm(h@Wp + bp). h round-trips LDS. GN fused in epilogue.
// ---------------------------------------------------------------------------
__global__ __launch_bounds__(512, 2) void mlp(
    const float* __restrict__ Xp,
    const _Float16* __restrict__ WfT, const float* __restrict__ bf,
    const _Float16* __restrict__ WpT, const float* __restrict__ bp,
    const float* __restrict__ gamma, const float* __restrict__ beta,
    float* __restrict__ out)
{
  __shared__ _Float16 As[32][520];
  const int M0 = blockIdx.x * 32;
  const int tid = threadIdx.x;
  const int lane = tid & 63;
  const int w = tid >> 6;
  const int lr = lane & 15;
  const int lkb = lane >> 4;
  const size_t CH = (size_t)NROWS * 512;

#pragma unroll
  for (int j = 0; j < 4; ++j) {
    int idx = tid + 512 * j;
    int r = idx >> 6, c16 = idx & 63;
    size_t off = (size_t)(M0 + r) * 512 + c16 * 8;
    float a8[8] = {0.f, 0.f, 0.f, 0.f, 0.f, 0.f, 0.f, 0.f};
#pragma unroll
    for (int c = 0; c < 4; ++c) {
      float4 f0 = *(const float4*)(Xp + (size_t)c * CH + off);
      float4 f1 = *(const float4*)(Xp + (size_t)c * CH + off + 4);
      a8[0] += f0.x; a8[1] += f0.y; a8[2] += f0.z; a8[3] += f0.w;
      a8[4] += f1.x; a8[5] += f1.y; a8[6] += f1.z; a8[7] += f1.w;
    }
    half8 h;
#pragma unroll
    for (int m = 0; m < 8; ++m) h[m] = (_Float16)a8[m];
    *(half8*)&As[r][c16 * 8] = h;
  }
  __syncthreads();

  f32x4 acc[2][4] = {};
  for (int ks = 0; ks < 16; ++ks) {
    half8 a0 = *(const half8*)&As[lr][ks * 32 + lkb * 8];
    half8 a1 = *(const half8*)&As[16 + lr][ks * 32 + lkb * 8];
#pragma unroll
    for (int nt = 0; nt < 4; ++nt) {
      half8 b = *(const half8*)(WfT + (size_t)(w * 64 + nt * 16 + lr) * 512 +
                                ks * 32 + lkb * 8);
      acc[0][nt] = mfma16(a0, b, acc[0][nt]);
      acc[1][nt] = mfma16(a1, b, acc[1][nt]);
    }
  }
  __syncthreads();   // done reading As

#pragma unroll
  for (int mt = 0; mt < 2; ++mt)
#pragma unroll
    for (int nt = 0; nt < 4; ++nt) {
      const int col = w * 64 + nt * 16 + lr;
      const float bias = bf[col];
#pragma unroll
      for (int i = 0; i < 4; ++i) {
        float v = acc[mt][nt][i] + bias;
        v = 0.5f * v * (1.0f + erff(v * 0.70710678118f));
        As[mt * 16 + lkb * 4 + i][col] = (_Float16)v;
      }
    }
  __syncthreads();

  f32x4 acc2[2][4] = {};
  for (int ks = 0; ks < 16; ++ks) {
    half8 a0 = *(const half8*)&As[lr][ks * 32 + lkb * 8];
    half8 a1 = *(const half8*)&As[16 + lr][ks * 32 + lkb * 8];
#pragma unroll
    for (int nt = 0; nt < 4; ++nt) {
      half8 b = *(const half8*)(WpT + (size_t)(w * 64 + nt * 16 + lr) * 512 +
                                ks * 32 + lkb * 8);
      acc2[0][nt] = mfma16(a0, b, acc2[0][nt]);
      acc2[1][nt] = mfma16(a1, b, acc2[1][nt]);
    }
  }

#pragma unroll
  for (int mt = 0; mt < 2; ++mt) {
    float vv[4][4];
#pragma unroll
    for (int nt = 0; nt < 4; ++nt) {
      const float bias = bp[w * 64 + nt * 16 + lr];
#pragma unroll
      for (int i = 0; i < 4; ++i) vv[nt][i] = acc2[mt][nt][i] + bias;
    }
#pragma unroll
    for (int i = 0; i < 4; ++i) {
      float s0 = vv[0][i] + vv[1][i];
      float q0 = vv[0][i] * vv[0][i] + vv[1][i] * vv[1][i];
      float s1 = vv[2][i] + vv[3][i];
      float q1 = vv[2][i] * vv[2][i] + vv[3][i] * vv[3][i];
#pragma unroll
      for (int m = 1; m <= 8; m <<= 1) {
        s0 += __shfl_xor(s0, m); q0 += __shfl_xor(q0, m);
        s1 += __shfl_xor(s1, m); q1 += __shfl_xor(q1, m);
      }
      const float mu0 = s0 * (1.0f / 32.0f);
      const float rs0 = rsqrtf(q0 * (1.0f / 32.0f) - mu0 * mu0 + 1e-5f);
      const float mu1 = s1 * (1.0f / 32.0f);
      const float rs1 = rsqrtf(q1 * (1.0f / 32.0f) - mu1 * mu1 + 1e-5f);
      const int row = M0 + mt * 16 + lkb * 4 + i;
#pragma unroll
      for (int nt = 0; nt < 4; ++nt) {
        const int col = w * 64 + nt * 16 + lr;
        const float mu = (nt < 2) ? mu0 : mu1;
        const float rs = (nt < 2) ? rs0 : rs1;
        out[(size_t)row * 512 + col] =
            (vv[nt][i] - mu) * rs * gamma[col] + beta[col];
      }
    }
  }
}

// ---------------------------------------------------------------------------
extern "C" void kernel_launch(void* const* d_in, const int* in_sizes, int n_in,
                              void* d_out, int out_size, void* d_ws, size_t ws_size,
                              hipStream_t stream)
{
  const float* x  = (const float*)d_in[0];
  const float* Dm = (const float*)d_in[1];
  const float* Wq = (const float*)d_in[2];
  const float* bq = (const float*)d_in[3];
  const float* Wk = (const float*)d_in[4];
  const float* bk = (const float*)d_in[5];
  const float* Wv = (const float*)d_in[6];
  const float* bv = (const float*)d_in[7];
  const float* Wf = (const float*)d_in[8];
  const float* bf = (const float*)d_in[9];
  const float* Wp = (const float*)d_in[10];
  const float* bp = (const float*)d_in[11];
  const float* gamma = (const float*)d_in[12];
  const float* beta  = (const float*)d_in[13];

  char* ws = (char*)d_ws;
  const size_t MB = 1024 * 1024;
  _Float16* xh  = (_Float16*)(ws);               //  8 MB
  _Float16* WT  = (_Float16*)(ws + 8 * MB);      //  2.62 MB
  _Float16* Qh  = (_Float16*)(ws + 11 * MB);     //  8 MB
  _Float16* Kh  = (_Float16*)(ws + 19 * MB);     //  8 MB
  _Float16* Vt  = (_Float16*)(ws + 27 * MB);     //  8 MB (V transposed [n][m])
  float*    Xp  = (float*)   (ws + 35 * MB);     //  4 x 16 MB partials

  hipLaunchKernelGGL(prep, dim3(576), dim3(256), 0, stream,
                     x, Wq, Wk, Wv, Wf, Wp, xh, WT);
  hipLaunchKernelGGL(qkv, dim3(256), dim3(512), 0, stream,
                     xh, WT, bq, bk, bv, Qh, Kh, Vt);
  hipLaunchKernelGGL(retention, dim3(512), dim3(512), 0, stream,
                     Qh, Kh, Vt, Dm, Xp);
  hipLaunchKernelGGL(mlp, dim3(256), dim3(512), 0, stream,
                     Xp, WT + 3 * 262144, bf, WT + 4 * 262144, bp,
                     gamma, beta, (float*)d_out);
}